// Round 15
// baseline (348.062 us; speedup 1.0000x reference)
//
#include <hip/hip_runtime.h>

#define NDIM 2048
#define FDIM 64
#define KDIM 8
#define BDIM 32
#define TN   16     // tile rows (n)
#define TM   256    // tile cols (m): one store inst = one full row = 1 KB
#define BFROW 72    // bf16 elems per staging row (64 + 8 pad)
#define PROW  260   // f32 elems per epilogue-panel row (256 + 4)
#define PLANES 4    // b-planes per epilogue pass
#define NTILE 2     // tiles per persistent block (grid 512 = 2 blocks/CU)

typedef __attribute__((ext_vector_type(8))) short short8;
typedef __attribute__((ext_vector_type(4))) float f32x4;

static __device__ __forceinline__ unsigned short f2bf(float x) {
    unsigned u = __float_as_uint(x);                 // RNE to bf16
    return (unsigned short)((u + 0x7fffu + ((u >> 16) & 1u)) >> 16);
}

// ---------------------------------------------------------------------------
// R15 = R13 (best PASS, 124.8us) made PERSISTENT: 512 blocks (exactly 2/CU,
// ONE residency round), each processing 2 tiles back-to-back. Rationale
// (timeline model): with 2 lockstep rounds, the ~15us cov phase is a store-
// pipe bubble paid twice; persistent blocks pay it once -- tile-1's stores
// (never vmcnt-drained at barriers) drain underneath tile-2's cov phase.
// Tile loop carries no acc indexing (k-loop fully unrolled inside: rule #20).
// LDS cross-tile hazard covered by the epilogue's final lgkmcnt+barrier.
// Mix is SCALAR FMAs only (f32x4 vector-mix of acc = proven miscompile,
// R6/R7/R9 vs R14).
// ---------------------------------------------------------------------------
__global__ __launch_bounds__(256, 2) void rfm_fused_mfma(
    const float* __restrict__ p, const float* __restrict__ L,
    const float* __restrict__ sr, float* __restrict__ out)
{
    __shared__ float pl[BDIM * KDIM];
    __shared__ __align__(16) char smem[PLANES * TN * PROW * 4];   // 66560 B

    unsigned short* const An = (unsigned short*)smem;       // [TN][BFROW] bf16
    unsigned short* const Am = An + TN * BFROW;             // [TM][BFROW] bf16
    float* const Parr0 = (float*)smem;                      // 4 panels [TN][PROW]
    float* const Parr1 = Parr0 + TN * PROW;
    float* const Parr2 = Parr1 + TN * PROW;
    float* const Parr3 = Parr2 + TN * PROW;
    float* const Parr[PLANES] = { Parr0, Parr1, Parr2, Parr3 };

    const int t  = threadIdx.x;
    const int lane = t & 63;
    const int w   = t >> 6;        // wave 0..3: cols w*64..w*64+63
    const int l15 = lane & 15;
    const int l4  = lane >> 4;     // 0..3

    pl[t] = p[t];                  // covered by first __syncthreads below

    #pragma unroll 1
    for (int tt = 0; tt < NTILE; ++tt) {
        const int tile = (int)blockIdx.x + tt * 512;
        const int m0 = (tile & 7) * TM;
        const int n0 = (tile >> 3) * TN;

        f32x4 acc[KDIM][4];
        #pragma unroll
        for (int k = 0; k < KDIM; ++k)
            #pragma unroll
            for (int j = 0; j < 4; ++j) acc[k][j] = (f32x4){0.f, 0.f, 0.f, 0.f};

        // ---- 1) cov phase: FULL k-unroll (static acc indexing) ----
        #pragma unroll
        for (int k = 0; k < KDIM; ++k) {
            const float* Lk = L + (size_t)k * (NDIM * FDIM);

            // An: 16 rows x 16 float4 = 256 float4 (1/thread)
            {
                const int row = t >> 4;
                const int fc  = (t & 15) << 2;
                const float4 va = *(const float4*)&Lk[(size_t)(n0 + row) * FDIM + fc];
                ushort4 ua;
                ua.x = f2bf(va.x); ua.y = f2bf(va.y); ua.z = f2bf(va.z); ua.w = f2bf(va.w);
                *(ushort4*)&An[row * BFROW + fc] = ua;
            }
            // Am: 256 rows x 16 float4 = 4096 float4 (16/thread)
            #pragma unroll
            for (int r = 0; r < 16; ++r) {
                const int idx = t + r * 256;
                const int row = idx >> 4;
                const int fc  = (idx & 15) << 2;
                const float4 vb = *(const float4*)&Lk[(size_t)(m0 + row) * FDIM + fc];
                ushort4 ub;
                ub.x = f2bf(vb.x); ub.y = f2bf(vb.y); ub.z = f2bf(vb.z); ub.w = f2bf(vb.w);
                *(ushort4*)&Am[row * BFROW + fc] = ub;
            }
            __syncthreads();

            short8 af[2], bv[4][2];
            #pragma unroll
            for (int s = 0; s < 2; ++s)
                af[s] = *(const short8*)&An[l15 * BFROW + s * 32 + l4 * 8];
            #pragma unroll
            for (int j = 0; j < 4; ++j)
                #pragma unroll
                for (int s = 0; s < 2; ++s)
                    bv[j][s] = *(const short8*)
                        &Am[(w * 64 + j * 16 + l15) * BFROW + s * 32 + l4 * 8];
            #pragma unroll
            for (int j = 0; j < 4; ++j)
                #pragma unroll
                for (int s = 0; s < 2; ++s)
                    acc[k][j] = __builtin_amdgcn_mfma_f32_16x16x32_bf16(
                        af[s], bv[j][s], acc[k][j], 0, 0, 0);
            __syncthreads();   // panels consumed; next k (or epilogue) may reuse
        }

        // Diagonal: D row = n-local = l4*4+reg, col = m-local = w*64+j*16+l15.
        #pragma unroll
        for (int j = 0; j < 4; ++j)
            #pragma unroll
            for (int reg = 0; reg < 4; ++reg) {
                const int gn = n0 + l4 * 4 + reg;
                const int gm = m0 + w * 64 + j * 16 + l15;
                if (gn == gm) {
                    #pragma unroll
                    for (int k = 0; k < KDIM; ++k) {
                        const float q = sr[k * NDIM + gn];
                        acc[k][j][reg] += q * q;
                    }
                }
            }

        // ---- 2) epilogue: 4 planes/pass x 8 passes (verbatim R13) ----
        const size_t NN = (size_t)NDIM * NDIM;
        const int scr = l4 * 4;                 // scatter row base (+reg)
        const int scc = w * 64 + l15;           // scatter col base (+j*16)
        float* const obase = out + (size_t)n0 * NDIM + m0 + lane * 4;

        #pragma unroll 1
        for (int b = 0; b < BDIM; b += PLANES) {
            // mix (SCALAR FMAs, static acc indices) + scatter
            #pragma unroll
            for (int u = 0; u < PLANES; ++u) {
                float pb[KDIM];
                #pragma unroll
                for (int k = 0; k < KDIM; ++k) pb[k] = pl[(b + u) * KDIM + k];
                float* const Pu = Parr[u];
                #pragma unroll
                for (int j = 0; j < 4; ++j)
                    #pragma unroll
                    for (int reg = 0; reg < 4; ++reg) {
                        float v = 0.0f;
                        #pragma unroll
                        for (int k = 0; k < KDIM; ++k)
                            v += pb[k] * acc[k][j][reg];
                        Pu[(scr + reg) * PROW + scc + j * 16] = v;
                    }
            }
            asm volatile("s_waitcnt lgkmcnt(0)" ::: "memory");  // ds_writes done
            __builtin_amdgcn_s_barrier();
            __builtin_amdgcn_sched_barrier(0);

            // readback + store: one inst = one full row = 1 KB contiguous
            #pragma unroll
            for (int u = 0; u < PLANES; ++u) {
                const float* const Pu = Parr[u];
                const size_t boff = (size_t)(b + u) * NN;
                #pragma unroll
                for (int rr = 0; rr < 4; ++rr) {
                    const int row = w + 4 * rr;
                    const f32x4 wv = *(const f32x4*)&Pu[row * PROW + lane * 4];
                    *(f32x4*)(obase + boff + (size_t)row * NDIM) = wv;
                }
            }
            asm volatile("s_waitcnt lgkmcnt(0)" ::: "memory");  // ds_reads done
            __builtin_amdgcn_s_barrier();                        // safe to reuse
            __builtin_amdgcn_sched_barrier(0);
        }
        // next tile's staging is safe: last barrier ordered all LDS reads;
        // global stores stay in flight and drain under tile tt+1's cov phase.
    }
}

extern "C" void kernel_launch(void* const* d_in, const int* in_sizes, int n_in,
                              void* d_out, int out_size, void* d_ws, size_t ws_size,
                              hipStream_t stream)
{
    const float* p  = (const float*)d_in[0];   // (B,K) = (32,8)
    const float* L  = (const float*)d_in[1];   // (K,N,F) = (8,2048,64)
    const float* sr = (const float*)d_in[2];   // (K,N)   = (8,2048)
    float* out = (float*)d_out;                // (B,N,N) = (32,2048,2048)

    hipLaunchKernelGGL(rfm_fused_mfma, dim3(512), dim3(256), 0, stream,
                       p, L, sr, out);
}

// Round 16
// 119.592 us; speedup vs baseline: 2.9104x; 2.9104x over previous
//
#include <hip/hip_runtime.h>

#define NDIM 2048
#define FDIM 64
#define KDIM 8
#define BDIM 32
#define TN   16     // tile rows (n)
#define TM   256    // tile cols (m) -> 1 KB contiguous per output row segment
#define BFROW 72    // bf16 elems per staging row (64 + 8 pad)
#define PROW  260   // f32 elems per epilogue-panel row (256 + 4)
#define PLANES 4    // b-planes per epilogue pass

typedef __attribute__((ext_vector_type(8))) short short8;
typedef __attribute__((ext_vector_type(4))) float f32x4;

static __device__ __forceinline__ unsigned short f2bf(float x) {
    unsigned u = __float_as_uint(x);                 // RNE to bf16
    return (unsigned short)((u + 0x7fffu + ((u >> 16) & 1u)) >> 16);
}

// ---------------------------------------------------------------------------
// R16 = R13 VERBATIM (best PASS, 124.8us; R15's persistent wrapper spilled:
// VGPR 128 + 133MB scratch writes -> reverted) with ONE change: epilogue
// stores are __builtin_nontemporal_store. Mechanism under test: 537MB of
// write-allocate traffic thrashes the 4MB/XCD L2 and evicts the L panels the
// cov phase re-reads; NT stores bypass L2 allocation for the write-once
// output. Everything else identical: 16x256 tile, full k-unroll (static acc
// -> registers, rule #20), scalar mix (f32x4 vector-mix of acc = proven
// miscompile R6/R7/R9), LDS scatter -> 1KB-row readback stores, lgkmcnt-only
// barriers (stores never drained).
// ---------------------------------------------------------------------------
__global__ __launch_bounds__(256, 2) void rfm_fused_mfma(
    const float* __restrict__ p, const float* __restrict__ L,
    const float* __restrict__ sr, float* __restrict__ out)
{
    __shared__ float pl[BDIM * KDIM];
    __shared__ __align__(16) char smem[PLANES * TN * PROW * 4];   // 66560 B

    unsigned short* const An = (unsigned short*)smem;       // [TN][BFROW] bf16
    unsigned short* const Am = An + TN * BFROW;             // [TM][BFROW] bf16
    float* const Parr0 = (float*)smem;                      // 4 panels [TN][PROW]
    float* const Parr1 = Parr0 + TN * PROW;
    float* const Parr2 = Parr1 + TN * PROW;
    float* const Parr3 = Parr2 + TN * PROW;

    const int m0 = blockIdx.x * TM;
    const int n0 = blockIdx.y * TN;
    const int t  = threadIdx.x;
    const int lane = t & 63;
    const int w   = t >> 6;        // wave 0..3: cols w*64..w*64+63
    const int l15 = lane & 15;
    const int l4  = lane >> 4;     // 0..3

    pl[t] = p[t];                  // covered by first __syncthreads below

    f32x4 acc[KDIM][4];
    #pragma unroll
    for (int k = 0; k < KDIM; ++k)
        #pragma unroll
        for (int j = 0; j < 4; ++j) acc[k][j] = (f32x4){0.f, 0.f, 0.f, 0.f};

    // ---- 1) cov phase: FULL unroll (static acc indexing; rule #20) ----
    #pragma unroll
    for (int k = 0; k < KDIM; ++k) {
        const float* Lk = L + (size_t)k * (NDIM * FDIM);

        // An: 16 rows x 16 float4 = 256 float4 (1/thread)
        {
            const int row = t >> 4;
            const int fc  = (t & 15) << 2;
            const float4 va = *(const float4*)&Lk[(size_t)(n0 + row) * FDIM + fc];
            ushort4 ua;
            ua.x = f2bf(va.x); ua.y = f2bf(va.y); ua.z = f2bf(va.z); ua.w = f2bf(va.w);
            *(ushort4*)&An[row * BFROW + fc] = ua;
        }
        // Am: 256 rows x 16 float4 = 4096 float4 (16/thread)
        #pragma unroll
        for (int r = 0; r < 16; ++r) {
            const int idx = t + r * 256;
            const int row = idx >> 4;
            const int fc  = (idx & 15) << 2;
            const float4 vb = *(const float4*)&Lk[(size_t)(m0 + row) * FDIM + fc];
            ushort4 ub;
            ub.x = f2bf(vb.x); ub.y = f2bf(vb.y); ub.z = f2bf(vb.z); ub.w = f2bf(vb.w);
            *(ushort4*)&Am[row * BFROW + fc] = ub;
        }
        __syncthreads();

        short8 af[2], bv[4][2];
        #pragma unroll
        for (int s = 0; s < 2; ++s)
            af[s] = *(const short8*)&An[l15 * BFROW + s * 32 + l4 * 8];
        #pragma unroll
        for (int j = 0; j < 4; ++j)
            #pragma unroll
            for (int s = 0; s < 2; ++s)
                bv[j][s] = *(const short8*)
                    &Am[(w * 64 + j * 16 + l15) * BFROW + s * 32 + l4 * 8];
        #pragma unroll
        for (int j = 0; j < 4; ++j)
            #pragma unroll
            for (int s = 0; s < 2; ++s)
                acc[k][j] = __builtin_amdgcn_mfma_f32_16x16x32_bf16(
                    af[s], bv[j][s], acc[k][j], 0, 0, 0);
        __syncthreads();   // panels consumed; next k (or epilogue) may overwrite
    }

    // Diagonal: D row = n-local = l4*4+reg, col = m-local = w*64+j*16+l15.
    #pragma unroll
    for (int j = 0; j < 4; ++j)
        #pragma unroll
        for (int reg = 0; reg < 4; ++reg) {
            const int gn = n0 + l4 * 4 + reg;
            const int gm = m0 + w * 64 + j * 16 + l15;
            if (gn == gm) {
                #pragma unroll
                for (int k = 0; k < KDIM; ++k) {
                    const float q = sr[k * NDIM + gn];
                    acc[k][j][reg] += q * q;
                }
            }
        }

    // ---- 2) epilogue: 4 planes/pass x 8 passes (R13 shape, NT stores) ----
    const size_t NN = (size_t)NDIM * NDIM;
    float* const Parr[PLANES] = { Parr0, Parr1, Parr2, Parr3 };
    const int scr = l4 * 4;                 // scatter row base (+reg)
    const int scc = w * 64 + l15;           // scatter col base (+j*16)
    float* const obase = out + (size_t)n0 * NDIM + m0 + lane * 4;

    #pragma unroll 1
    for (int b = 0; b < BDIM; b += PLANES) {
        // mix (SCALAR FMAs, all acc indices static) + scatter
        #pragma unroll
        for (int u = 0; u < PLANES; ++u) {
            float pb[KDIM];
            #pragma unroll
            for (int k = 0; k < KDIM; ++k) pb[k] = pl[(b + u) * KDIM + k];
            float* const Pu = Parr[u];
            #pragma unroll
            for (int j = 0; j < 4; ++j)
                #pragma unroll
                for (int reg = 0; reg < 4; ++reg) {
                    float v = 0.0f;
                    #pragma unroll
                    for (int k = 0; k < KDIM; ++k) v += pb[k] * acc[k][j][reg];
                    Pu[(scr + reg) * PROW + scc + j * 16] = v;
                }
        }
        asm volatile("s_waitcnt lgkmcnt(0)" ::: "memory");  // my ds_writes done
        __builtin_amdgcn_s_barrier();                        // all writes done
        __builtin_amdgcn_sched_barrier(0);

        // readback + store: 4 rows per wave per plane, 1 KB contiguous/inst
        #pragma unroll
        for (int u = 0; u < PLANES; ++u) {
            const float* const Pu = Parr[u];
            const size_t boff = (size_t)(b + u) * NN;
            #pragma unroll
            for (int rr = 0; rr < 4; ++rr) {
                const int row = w + 4 * rr;
                const f32x4 wv = *(const f32x4*)&Pu[row * PROW + lane * 4];
                __builtin_nontemporal_store(wv,
                    (f32x4*)(obase + boff + (size_t)row * NDIM));
            }
        }
        asm volatile("s_waitcnt lgkmcnt(0)" ::: "memory");  // my ds_reads done
        __builtin_amdgcn_s_barrier();                        // safe to overwrite
        __builtin_amdgcn_sched_barrier(0);
    }
}

extern "C" void kernel_launch(void* const* d_in, const int* in_sizes, int n_in,
                              void* d_out, int out_size, void* d_ws, size_t ws_size,
                              hipStream_t stream)
{
    const float* p  = (const float*)d_in[0];   // (B,K) = (32,8)
    const float* L  = (const float*)d_in[1];   // (K,N,F) = (8,2048,64)
    const float* sr = (const float*)d_in[2];   // (K,N)   = (8,2048)
    float* out = (float*)d_out;                // (B,N,N) = (32,2048,2048)

    dim3 grid(NDIM / TM, NDIM / TN);           // 8 x 128 = 1024 blocks
    hipLaunchKernelGGL(rfm_fused_mfma, grid, dim3(256), 0, stream,
                       p, L, sr, out);
}